// Round 1
// baseline (1052.187 us; speedup 1.0000x reference)
//
#include <hip/hip_runtime.h>
#include <math.h>

#define BB 512        // batch
#define DD 512        // dim
#define CC 100000     // classes
#define MARGIN 0.2f
#define CLIP_EPS 1e-8f
#define NCHUNK 391    // ceil(100000 / 256)

// workspace layout (float element offsets)
#define XN_OFF   0
#define WINV_OFF (BB*DD)                 // 262144
#define MP_OFF   (WINV_OFF + CC)         // + 100000
#define ZP_OFF   (MP_OFF + NCHUNK*BB)
#define S2_OFF   (ZP_OFF + NCHUNK*BB)
#define S3_OFF   (S2_OFF + NCHUNK*BB)

// ---------------- kernel 1: normalize x rows, zero the output ----------------
__global__ __launch_bounds__(256) void k_norm_x(const float* __restrict__ x,
                                                float* __restrict__ ws,
                                                float* __restrict__ out) {
    int row = blockIdx.x;
    int tid = threadIdx.x;
    float v0 = x[row * DD + tid];
    float v1 = x[row * DD + tid + 256];
    float ss = v0 * v0 + v1 * v1;
    for (int m = 1; m < 64; m <<= 1) ss += __shfl_xor(ss, m, 64);
    __shared__ float sm[4];
    int wid = tid >> 6, lane = tid & 63;
    if (lane == 0) sm[wid] = ss;
    __syncthreads();
    float tot = sm[0] + sm[1] + sm[2] + sm[3];
    float inv = 1.0f / fmaxf(sqrtf(tot), 1e-12f);
    ws[XN_OFF + row * DD + tid]       = v0 * inv;
    ws[XN_OFF + row * DD + tid + 256] = v1 * inv;
    if (row == 0 && tid == 0) out[0] = 0.0f;
}

// ---------------- kernel 1b: 1 / ||w_c|| for all classes ----------------
__global__ __launch_bounds__(256) void k_wnorm(const float* __restrict__ w,
                                               float* __restrict__ ws) {
    int wid = threadIdx.x >> 6, lane = threadIdx.x & 63;
    int row = blockIdx.x * 4 + wid;
    if (row >= CC) return;
    const float4* wr = (const float4*)(w + (size_t)row * DD);
    float4 a = wr[lane];
    float4 b = wr[lane + 64];
    float ss = a.x*a.x + a.y*a.y + a.z*a.z + a.w*a.w
             + b.x*b.x + b.y*b.y + b.z*b.z + b.w*b.w;
    for (int m = 1; m < 64; m <<= 1) ss += __shfl_xor(ss, m, 64);
    if (lane == 0) ws[WINV_OFF + row] = 1.0f / fmaxf(sqrtf(ss), 1e-12f);
}

// ---------------- kernel 2: tiled logits + fused online stats ----------------
// grid (NCHUNK, 8). Block 256 = 16x16 threads; each thread owns 4 rows x 4 cols.
// Per block: 64 rows x 256 cols (4 sub-tiles of 64 cols), K = 512 in 8 LDS tiles.
// Emits per-(chunk,row): m, Z=sum e^(s-m), S2=sum e^(2(s-m)), S3=sum e^(3(s-m)).
__global__ __launch_bounds__(256) void k_stats(const float* __restrict__ w,
                                               float* __restrict__ ws,
                                               const float* __restrict__ rescale_p) {
    __shared__ __align__(16) float xs[64][68];  // [k][row], padded
    __shared__ __align__(16) float wt[64][68];  // [k][col], padded
    int tid = threadIdx.x;
    int tx = tid & 15, ty = tid >> 4;
    int rowbase = blockIdx.y * 64;
    float rescale = rescale_p[0];
    const float* xn = ws + XN_OFF;

    float rm[4], rz[4], rs2[4], rs3[4];
#pragma unroll
    for (int i = 0; i < 4; i++) { rm[i] = -1e30f; rz[i] = 0.f; rs2[i] = 0.f; rs3[i] = 0.f; }

    for (int sub = 0; sub < 4; ++sub) {
        int colbase = blockIdx.x * 256 + sub * 64;
        float acc[4][4] = {};
        for (int kt = 0; kt < 8; ++kt) {
            __syncthreads();   // previous tile fully consumed
#pragma unroll
            for (int i = 0; i < 4; i++) {
                int f = i * 256 + tid;          // float4 id in [0,1024)
                int r = f >> 4, c4 = f & 15;    // 16 float4 per 64-wide row
                float4 xv = *(const float4*)(xn + (size_t)(rowbase + r) * DD + kt * 64 + c4 * 4);
                xs[c4*4+0][r] = xv.x; xs[c4*4+1][r] = xv.y;
                xs[c4*4+2][r] = xv.z; xs[c4*4+3][r] = xv.w;
                int cg = colbase + r;
                float4 wv = make_float4(0.f, 0.f, 0.f, 0.f);
                if (cg < CC) wv = *(const float4*)(w + (size_t)cg * DD + kt * 64 + c4 * 4);
                wt[c4*4+0][r] = wv.x; wt[c4*4+1][r] = wv.y;
                wt[c4*4+2][r] = wv.z; wt[c4*4+3][r] = wv.w;
            }
            __syncthreads();   // tiles ready
#pragma unroll 8
            for (int k = 0; k < 64; k++) {
                float4 a  = *(const float4*)&xs[k][ty * 4];
                float4 bb = *(const float4*)&wt[k][tx * 4];
                float av[4] = {a.x, a.y, a.z, a.w};
                float bv[4] = {bb.x, bb.y, bb.z, bb.w};
#pragma unroll
                for (int i = 0; i < 4; i++)
#pragma unroll
                    for (int j = 0; j < 4; j++)
                        acc[i][j] = fmaf(av[i], bv[j], acc[i][j]);
            }
        }
        // fold this sub-tile's 4 cols into running per-row stats
#pragma unroll
        for (int i = 0; i < 4; i++) {
            float s[4];
#pragma unroll
            for (int j = 0; j < 4; j++) {
                int cg = colbase + tx * 4 + j;
                float sv = -1e30f;
                if (cg < CC) {
                    float cosv = acc[i][j] * ws[WINV_OFF + cg];
                    cosv = fminf(fmaxf(cosv, -1.0f + CLIP_EPS), 1.0f - CLIP_EPS);
                    sv = rescale * cosv;
                }
                s[j] = sv;
            }
            float m4 = fmaxf(fmaxf(s[0], s[1]), fmaxf(s[2], s[3]));
            float z = 0.f, q2 = 0.f, q3 = 0.f;
#pragma unroll
            for (int j = 0; j < 4; j++) {
                float t = (s[j] > -1e29f) ? __expf(s[j] - m4) : 0.0f;
                z += t; float t2 = t * t; q2 += t2; q3 += t2 * t;
            }
            float mo = fmaxf(rm[i], m4);
            float e1 = (rm[i] > -1e29f) ? __expf(rm[i] - mo) : 0.0f;
            float e2 = (m4    > -1e29f) ? __expf(m4    - mo) : 0.0f;
            rz[i]  = rz[i]  * e1       + z  * e2;
            rs2[i] = rs2[i] * e1 * e1  + q2 * e2 * e2;
            rs3[i] = rs3[i] * e1*e1*e1 + q3 * e2*e2*e2;
            rm[i]  = mo;
        }
    }
    // reduce across the 16 lanes (tx) sharing the same 4 rows
#pragma unroll
    for (int msk = 1; msk < 16; msk <<= 1) {
#pragma unroll
        for (int i = 0; i < 4; i++) {
            float om = __shfl_xor(rm[i],  msk, 64);
            float oz = __shfl_xor(rz[i],  msk, 64);
            float o2 = __shfl_xor(rs2[i], msk, 64);
            float o3 = __shfl_xor(rs3[i], msk, 64);
            float mo = fmaxf(rm[i], om);
            float e1 = (rm[i] > -1e29f) ? __expf(rm[i] - mo) : 0.0f;
            float e2 = (om    > -1e29f) ? __expf(om    - mo) : 0.0f;
            rz[i]  = rz[i]  * e1      + oz * e2;
            rs2[i] = rs2[i] * e1*e1   + o2 * e2*e2;
            rs3[i] = rs3[i] * e1*e1*e1+ o3 * e2*e2*e2;
            rm[i]  = mo;
        }
    }
    if (tx == 0) {
        int chunk = blockIdx.x;
#pragma unroll
        for (int i = 0; i < 4; i++) {
            int rg = rowbase + ty * 4 + i;
            ws[MP_OFF + chunk * BB + rg] = rm[i];
            ws[ZP_OFF + chunk * BB + rg] = rz[i];
            ws[S2_OFF + chunk * BB + rg] = rs2[i];
            ws[S3_OFF + chunk * BB + rg] = rs3[i];
        }
    }
}

// ---------------- kernel 3: combine partials, margin fixup, loss ----------------
__global__ __launch_bounds__(256) void k_final(const float* __restrict__ w,
                                               const int* __restrict__ y,
                                               const float* __restrict__ rescale_p,
                                               float* __restrict__ ws,
                                               float* __restrict__ out) {
    int b = blockIdx.x;
    int tid = threadIdx.x;
    int yb = y[b];
    const float* xn = ws + XN_OFF;

    // phase A: dot(x_n[b], w[yb]) and ||w[yb]||^2
    float d0 = 0.f, q0 = 0.f;
#pragma unroll
    for (int i = 0; i < 2; i++) {
        int idx = tid + i * 256;
        float xv = xn[b * DD + idx];
        float wv = w[(size_t)yb * DD + idx];
        d0 = fmaf(xv, wv, d0);
        q0 = fmaf(wv, wv, q0);
    }
    for (int m = 1; m < 64; m <<= 1) { d0 += __shfl_xor(d0, m, 64); q0 += __shfl_xor(q0, m, 64); }
    __shared__ float sd[4], sq[4], smm[4], szz[4], s22[4], s33[4];
    int wid = tid >> 6, lane = tid & 63;
    if (lane == 0) { sd[wid] = d0; sq[wid] = q0; }

    // phase B: merge per-chunk partials for this row
    float rm = -1e30f, rz = 0.f, r2 = 0.f, r3 = 0.f;
    for (int ch = tid; ch < NCHUNK; ch += 256) {
        float om = ws[MP_OFF + ch * BB + b];
        float oz = ws[ZP_OFF + ch * BB + b];
        float o2 = ws[S2_OFF + ch * BB + b];
        float o3 = ws[S3_OFF + ch * BB + b];
        float mo = fmaxf(rm, om);
        float e1 = (rm > -1e29f) ? __expf(rm - mo) : 0.0f;
        float e2 = (om > -1e29f) ? __expf(om - mo) : 0.0f;
        rz = rz * e1        + oz * e2;
        r2 = r2 * e1*e1     + o2 * e2*e2;
        r3 = r3 * e1*e1*e1  + o3 * e2*e2*e2;
        rm = mo;
    }
    for (int msk = 1; msk < 64; msk <<= 1) {
        float om = __shfl_xor(rm, msk, 64);
        float oz = __shfl_xor(rz, msk, 64);
        float o2 = __shfl_xor(r2, msk, 64);
        float o3 = __shfl_xor(r3, msk, 64);
        float mo = fmaxf(rm, om);
        float e1 = (rm > -1e29f) ? __expf(rm - mo) : 0.0f;
        float e2 = (om > -1e29f) ? __expf(om - mo) : 0.0f;
        rz = rz * e1       + oz * e2;
        r2 = r2 * e1*e1    + o2 * e2*e2;
        r3 = r3 * e1*e1*e1 + o3 * e2*e2*e2;
        rm = mo;
    }
    if (lane == 0) { smm[wid] = rm; szz[wid] = rz; s22[wid] = r2; s33[wid] = r3; }
    __syncthreads();

    if (tid == 0) {
        float M0 = smm[0], Z = szz[0], S2 = s22[0], S3 = s33[0];
#pragma unroll
        for (int k = 1; k < 4; k++) {
            float om = smm[k], oz = szz[k], o2 = s22[k], o3 = s33[k];
            float mo = fmaxf(M0, om);
            float e1 = (M0 > -1e29f) ? __expf(M0 - mo) : 0.0f;
            float e2 = (om > -1e29f) ? __expf(om - mo) : 0.0f;
            Z  = Z  * e1       + oz * e2;
            S2 = S2 * e1*e1    + o2 * e2*e2;
            S3 = S3 * e1*e1*e1 + o3 * e2*e2*e2;
            M0 = mo;
        }
        float dot = sd[0] + sd[1] + sd[2] + sd[3];
        float ssq = sq[0] + sq[1] + sq[2] + sq[3];
        float rescale = rescale_p[0];
        float winv = 1.0f / fmaxf(sqrtf(ssq), 1e-12f);
        float fc = dot * winv;
        fc = fminf(fmaxf(fc, -1.0f + CLIP_EPS), 1.0f - CLIP_EPS);
        float su  = rescale * fc;                                     // unmargined target logit
        float fcm = fc * cosf(MARGIN) - sqrtf(fmaxf(1.0f - fc * fc, 0.0f)) * sinf(MARGIN);
        float sm2 = rescale * fcm;                                    // margined target logit
        // swap target column's contribution from unmargined -> margined
        float eU = __expf(su - M0), eM = __expf(sm2 - M0);
        Z  += eM - eU;
        S2 += eM * eM - eU * eU;
        S3 += eM * eM * eM - eU * eU * eU;
        float py = eM / Z;
        // sum_c exp(p_c) = C + sum p + sum p^2/2 + sum p^3/6  (remainder < 1e-13)
        float sumexp = (float)CC + 1.0f + S2 / (2.0f * Z * Z) + S3 / (6.0f * Z * Z * Z);
        float nll = logf(sumexp) - py;
        atomicAdd(out, nll * (1.0f / (float)BB));
    }
}

extern "C" void kernel_launch(void* const* d_in, const int* in_sizes, int n_in,
                              void* d_out, int out_size, void* d_ws, size_t ws_size,
                              hipStream_t stream) {
    const float* x       = (const float*)d_in[0];
    const int*   y       = (const int*)  d_in[1];
    const float* w       = (const float*)d_in[2];
    const float* rescale = (const float*)d_in[3];
    float* out = (float*)d_out;
    float* ws  = (float*)d_ws;

    k_norm_x<<<dim3(BB), dim3(256), 0, stream>>>(x, ws, out);
    k_wnorm <<<dim3(CC / 4), dim3(256), 0, stream>>>(w, ws);
    k_stats <<<dim3(NCHUNK, 8), dim3(256), 0, stream>>>(w, ws, rescale);
    k_final <<<dim3(BB), dim3(256), 0, stream>>>(w, y, rescale, ws, out);
}

// Round 2
// 230.454 us; speedup vs baseline: 4.5657x; 4.5657x over previous
//
#include <hip/hip_runtime.h>
#include <math.h>

#define BB 512
#define DD 512
#define CC 100000
#define MARGIN 0.2f
#define CLIP_EPS 1e-8f
#define NCOLT 782            // ceil(CC/128)

typedef short short8 __attribute__((ext_vector_type(8)));
typedef float f32x4  __attribute__((ext_vector_type(4)));

// ---- workspace byte offsets ----
#define XNB_OFF  0u                       // ushort[512*512]  = 524288 B (bf16 normalized x)
#define WINV_OFF 524288u                  // float[100000]    = 400000 B
#define ZP_OFF   1048576u                 // float[NCOLT*512]
#define PSZ      (NCOLT * 512u * 4u)      // 1601536 B
#define S2P_OFF  (ZP_OFF + PSZ)
#define S3P_OFF  (ZP_OFF + 2u * PSZ)

__device__ inline unsigned short f2bf(float a) {
    unsigned u = __builtin_bit_cast(unsigned, a);
    return (unsigned short)((u + 0x7fffu + ((u >> 16) & 1u)) >> 16);
}
__device__ inline unsigned pk2(float a, float b) {
    return (unsigned)f2bf(a) | ((unsigned)f2bf(b) << 16);
}
__device__ inline float bf2f(unsigned short h) {
    unsigned u = ((unsigned)h) << 16;
    return __builtin_bit_cast(float, u);
}
// swizzled LDS element offset for [128][32] bf16 tiles; kk is a multiple of 8
__device__ inline int soff(int row, int kk) {
    return row * 32 + (kk ^ (((row >> 1) & 3) << 3));
}

// ---------------- kernel 1: normalize x rows -> bf16, zero out ----------------
__global__ __launch_bounds__(256) void k_norm_x(const float* __restrict__ x,
                                                char* __restrict__ wsb,
                                                float* __restrict__ out) {
    unsigned short* XNB = (unsigned short*)(wsb + XNB_OFF);
    int row = blockIdx.x, tid = threadIdx.x;
    float v0 = x[row * DD + tid];
    float v1 = x[row * DD + tid + 256];
    float ss = v0 * v0 + v1 * v1;
    for (int m = 1; m < 64; m <<= 1) ss += __shfl_xor(ss, m, 64);
    __shared__ float sm[4];
    int wid = tid >> 6, lane = tid & 63;
    if (lane == 0) sm[wid] = ss;
    __syncthreads();
    float inv = 1.0f / fmaxf(sqrtf(sm[0] + sm[1] + sm[2] + sm[3]), 1e-12f);
    XNB[row * DD + tid]       = f2bf(v0 * inv);
    XNB[row * DD + tid + 256] = f2bf(v1 * inv);
    if (row == 0 && tid == 0) out[0] = 0.0f;
}

// ---------------- kernel 1b: 1/||w_c|| ----------------
__global__ __launch_bounds__(256) void k_wnorm(const float* __restrict__ w,
                                               char* __restrict__ wsb) {
    float* WINV = (float*)(wsb + WINV_OFF);
    int wid = threadIdx.x >> 6, lane = threadIdx.x & 63;
    int row = blockIdx.x * 4 + wid;
    if (row >= CC) return;
    const float4* wr = (const float4*)(w + (size_t)row * DD);
    float4 a = wr[lane];
    float4 b = wr[lane + 64];
    float ss = a.x*a.x + a.y*a.y + a.z*a.z + a.w*a.w
             + b.x*b.x + b.y*b.y + b.z*b.z + b.w*b.w;
    for (int m = 1; m < 64; m <<= 1) ss += __shfl_xor(ss, m, 64);
    if (lane == 0) WINV[row] = 1.0f / fmaxf(sqrtf(ss), 1e-12f);
}

// ---------------- kernel 2: bf16 MFMA logits + fused stats ----------------
// grid (4 rowtiles fastest, 782 coltiles). 256 threads = 4 waves in 2x2.
// Per block: 128 rows x 128 cols, K=512 in 16 steps of BK=32.
// Emits per (coltile, global row): Z = sum e^(s-m), S2 = sum e^(2(s-m)), S3.
__global__ __launch_bounds__(256) void k_gemm(const float* __restrict__ w,
                                              const float* __restrict__ rescale_p,
                                              char* __restrict__ wsb) {
    __shared__ __align__(16) unsigned short As[128 * 32];
    __shared__ __align__(16) unsigned short Bs[128 * 32];
    __shared__ float st[2][2][64][3];

    const unsigned short* XNB = (const unsigned short*)(wsb + XNB_OFF);
    const float* WINV = (const float*)(wsb + WINV_OFF);
    float* ZP  = (float*)(wsb + ZP_OFF);
    float* S2P = (float*)(wsb + S2P_OFF);
    float* S3P = (float*)(wsb + S3P_OFF);

    int tid = threadIdx.x;
    int lane = tid & 63, wid = tid >> 6;
    int wr = wid >> 1, wc = wid & 1;
    int rowbase = blockIdx.x * 128;
    int colbase = blockIdx.y * 128;
    float rescale = rescale_p[0];

    // staging mapping: thread -> (row 0..127, half 0..1), 16 elements each
    int srow = tid & 127, half = tid >> 7;
    const uint4* asrc = (const uint4*)(XNB + (size_t)(rowbase + srow) * DD + half * 16);
    int cg = colbase + srow;
    int cgc = cg < CC ? cg : CC - 1;
    const float4* bsrc = (const float4*)(w + (size_t)cgc * DD + half * 16);
    int wo0 = soff(srow, half * 16);
    int wo1 = soff(srow, half * 16 + 8);

    // fragment read offsets (constant across K steps)
    int ro[4], co[4];
#pragma unroll
    for (int i = 0; i < 4; i++) {
        ro[i] = soff(wr * 64 + i * 16 + (lane & 15), (lane >> 4) * 8);
        co[i] = soff(wc * 64 + i * 16 + (lane & 15), (lane >> 4) * 8);
    }

    f32x4 acc[4][4];
#pragma unroll
    for (int i = 0; i < 4; i++)
#pragma unroll
        for (int j = 0; j < 4; j++) acc[i][j] = (f32x4){0.f, 0.f, 0.f, 0.f};

    uint4 Aa0, Ab0, Aa1, Ab1;
    float4 Bf0[4], Bf1[4];

    auto LOAD = [&](uint4& Aa, uint4& Ab, float4* Bf, int kt) {
        Aa = asrc[kt * 4];
        Ab = asrc[kt * 4 + 1];
#pragma unroll
        for (int i = 0; i < 4; i++) Bf[i] = bsrc[kt * 8 + i];
    };
    auto STORE = [&](const uint4& Aa, const uint4& Ab, const float4* Bf) {
        *(uint4*)&As[wo0] = Aa;
        *(uint4*)&As[wo1] = Ab;
        uint4 lo, hi;
        lo.x = pk2(Bf[0].x, Bf[0].y); lo.y = pk2(Bf[0].z, Bf[0].w);
        lo.z = pk2(Bf[1].x, Bf[1].y); lo.w = pk2(Bf[1].z, Bf[1].w);
        hi.x = pk2(Bf[2].x, Bf[2].y); hi.y = pk2(Bf[2].z, Bf[2].w);
        hi.z = pk2(Bf[3].x, Bf[3].y); hi.w = pk2(Bf[3].z, Bf[3].w);
        *(uint4*)&Bs[wo0] = lo;
        *(uint4*)&Bs[wo1] = hi;
    };
    auto COMPUTE = [&]() {
        short8 a[4], b[4];
#pragma unroll
        for (int i = 0; i < 4; i++) a[i] = *(const short8*)&As[ro[i]];
#pragma unroll
        for (int i = 0; i < 4; i++) b[i] = *(const short8*)&Bs[co[i]];
#pragma unroll
        for (int i = 0; i < 4; i++)
#pragma unroll
            for (int j = 0; j < 4; j++)
                acc[i][j] = __builtin_amdgcn_mfma_f32_16x16x32_bf16(a[i], b[j], acc[i][j], 0, 0, 0);
    };

    LOAD(Aa0, Ab0, Bf0, 0);
    for (int it = 0; it < 8; ++it) {
        int kt = it * 2;
        __syncthreads();                 // LDS consumed by previous compute
        STORE(Aa0, Ab0, Bf0);
        LOAD(Aa1, Ab1, Bf1, kt + 1);     // overlap next loads with compute
        __syncthreads();                 // tile ready
        COMPUTE();
        __syncthreads();
        STORE(Aa1, Ab1, Bf1);
        if (kt + 2 < 16) LOAD(Aa0, Ab0, Bf0, kt + 2);
        __syncthreads();
        COMPUTE();
    }

    // ---- epilogue: cos -> clip -> exp stats, per-row reduce ----
    float wv[4];
    int cvalid[4];
#pragma unroll
    for (int ni = 0; ni < 4; ni++) {
        int c = colbase + wc * 64 + ni * 16 + (lane & 15);
        cvalid[ni] = (c < CC);
        wv[ni] = cvalid[ni] ? WINV[c] : 0.0f;
    }
    float mref = fabsf(rescale);
#pragma unroll
    for (int mi = 0; mi < 4; mi++) {
#pragma unroll
        for (int reg = 0; reg < 4; reg++) {
            float zz = 0.f, q2 = 0.f, q3 = 0.f;
#pragma unroll
            for (int ni = 0; ni < 4; ni++) {
                if (cvalid[ni]) {
                    float cosv = acc[mi][ni][reg] * wv[ni];
                    cosv = fminf(fmaxf(cosv, -1.0f + CLIP_EPS), 1.0f - CLIP_EPS);
                    float e = __expf(rescale * cosv - mref);
                    zz += e;
                    float e2 = e * e;
                    q2 += e2;
                    q3 += e2 * e;
                }
            }
#pragma unroll
            for (int msk = 1; msk < 16; msk <<= 1) {
                zz += __shfl_xor(zz, msk, 64);
                q2 += __shfl_xor(q2, msk, 64);
                q3 += __shfl_xor(q3, msk, 64);
            }
            if ((lane & 15) == 0) {
                int rl = mi * 16 + (lane >> 4) * 4 + reg;
                st[wr][wc][rl][0] = zz;
                st[wr][wc][rl][1] = q2;
                st[wr][wc][rl][2] = q3;
            }
        }
    }
    __syncthreads();
    if (tid < 128) {
        int wrr = tid >> 6, rl = tid & 63;
        float Z  = st[wrr][0][rl][0] + st[wrr][1][rl][0];
        float S2 = st[wrr][0][rl][1] + st[wrr][1][rl][1];
        float S3 = st[wrr][0][rl][2] + st[wrr][1][rl][2];
        size_t gi = (size_t)blockIdx.y * BB + rowbase + tid;
        ZP[gi] = Z; S2P[gi] = S2; S3P[gi] = S3;
    }
}

// ---------------- kernel 3: combine partials, margin fixup, loss ----------------
__global__ __launch_bounds__(256) void k_final(const float* __restrict__ w,
                                               const int* __restrict__ y,
                                               const float* __restrict__ rescale_p,
                                               char* __restrict__ wsb,
                                               float* __restrict__ out) {
    const unsigned short* XNB = (const unsigned short*)(wsb + XNB_OFF);
    const float* ZP  = (const float*)(wsb + ZP_OFF);
    const float* S2P = (const float*)(wsb + S2P_OFF);
    const float* S3P = (const float*)(wsb + S3P_OFF);

    int b = blockIdx.x, tid = threadIdx.x;
    int yb = y[b];

    // dot(x_n[b], w[yb]) and ||w[yb]||^2
    float d0 = 0.f, q0 = 0.f;
#pragma unroll
    for (int i = 0; i < 2; i++) {
        int idx = tid + i * 256;
        float xv = bf2f(XNB[b * DD + idx]);
        float wvv = w[(size_t)yb * DD + idx];
        d0 = fmaf(xv, wvv, d0);
        q0 = fmaf(wvv, wvv, q0);
    }
    for (int m = 1; m < 64; m <<= 1) { d0 += __shfl_xor(d0, m, 64); q0 += __shfl_xor(q0, m, 64); }
    __shared__ float sd[4], sq[4], szs[4], s2s[4], s3s[4];
    int wid = tid >> 6, lane = tid & 63;
    if (lane == 0) { sd[wid] = d0; sq[wid] = q0; }

    // plain sums over coltile partials
    float rz = 0.f, r2 = 0.f, r3 = 0.f;
    for (int ch = tid; ch < NCOLT; ch += 256) {
        size_t gi = (size_t)ch * BB + b;
        rz += ZP[gi]; r2 += S2P[gi]; r3 += S3P[gi];
    }
    for (int m = 1; m < 64; m <<= 1) {
        rz += __shfl_xor(rz, m, 64);
        r2 += __shfl_xor(r2, m, 64);
        r3 += __shfl_xor(r3, m, 64);
    }
    if (lane == 0) { szs[wid] = rz; s2s[wid] = r2; s3s[wid] = r3; }
    __syncthreads();

    if (tid == 0) {
        float Z  = szs[0] + szs[1] + szs[2] + szs[3];
        float S2 = s2s[0] + s2s[1] + s2s[2] + s2s[3];
        float S3 = s3s[0] + s3s[1] + s3s[2] + s3s[3];
        float dot = sd[0] + sd[1] + sd[2] + sd[3];
        float ssq = sq[0] + sq[1] + sq[2] + sq[3];
        float rescale = rescale_p[0];
        float mref = fabsf(rescale);
        float winv = 1.0f / fmaxf(sqrtf(ssq), 1e-12f);
        float fc = fminf(fmaxf(dot * winv, -1.0f + CLIP_EPS), 1.0f - CLIP_EPS);
        float su = rescale * fc;
        float fcm = fc * cosf(MARGIN) - sqrtf(fmaxf(1.0f - fc * fc, 0.0f)) * sinf(MARGIN);
        float smv = rescale * fcm;
        // swap target column's contribution unmargined -> margined
        float eU = __expf(su - mref), eM = __expf(smv - mref);
        Z  += eM - eU;
        S2 += eM * eM - eU * eU;
        S3 += eM * eM * eM - eU * eU * eU;
        float py = eM / Z;
        // sum_c exp(p_c) = C + 1 + sum p^2/2 + sum p^3/6 (remainder < 1e-13)
        float sumexp = (float)CC + 1.0f + S2 / (2.0f * Z * Z) + S3 / (6.0f * Z * Z * Z);
        float nll = logf(sumexp) - py;
        atomicAdd(out, nll * (1.0f / (float)BB));
    }
}

extern "C" void kernel_launch(void* const* d_in, const int* in_sizes, int n_in,
                              void* d_out, int out_size, void* d_ws, size_t ws_size,
                              hipStream_t stream) {
    const float* x       = (const float*)d_in[0];
    const int*   y       = (const int*)  d_in[1];
    const float* w       = (const float*)d_in[2];
    const float* rescale = (const float*)d_in[3];
    float* out = (float*)d_out;
    char*  wsb = (char*)d_ws;

    k_norm_x<<<dim3(BB), dim3(256), 0, stream>>>(x, wsb, out);
    k_wnorm <<<dim3(CC / 4), dim3(256), 0, stream>>>(w, wsb);
    k_gemm  <<<dim3(4, NCOLT), dim3(256), 0, stream>>>(w, rescale, wsb);
    k_final <<<dim3(BB), dim3(256), 0, stream>>>(w, y, rescale, wsb, out);
}

// Round 3
// 171.998 us; speedup vs baseline: 6.1174x; 1.3399x over previous
//
#include <hip/hip_runtime.h>
#include <math.h>

#define BB 512
#define DD 512
#define CC 100000
#define CCPAD 100096          // 782 * 128
#define MARGIN 0.2f
#define CLIP_EPS 1e-8f
#define NCOLT 782             // ceil(CC/128)

typedef short short8 __attribute__((ext_vector_type(8)));
typedef float f32x4  __attribute__((ext_vector_type(4)));

// ---- workspace layout (byte offsets) ----
// common: XNB bf16[512*512] @0 ; ZP/S2P/S3P float[782*512] each
#define XNB_BYTES   524288u
#define P_BYTES     1601536u                      // 782*512*4
#define PBASE       XNB_BYTES
#define AUX_OFF     (PBASE + 3u * P_BYTES)        // 5,328,896
// new path: WNB bf16[100096*512] at AUX_OFF  (102,498,304 B)
// old path: WINV float[100000]   at AUX_OFF
#define NEED_NEW    (AUX_OFF + (size_t)CCPAD * DD * 2u)

__device__ inline unsigned short f2bf(float a) {
    unsigned u = __builtin_bit_cast(unsigned, a);
    return (unsigned short)((u + 0x7fffu + ((u >> 16) & 1u)) >> 16);
}
__device__ inline unsigned pk2(float a, float b) {
    return (unsigned)f2bf(a) | ((unsigned)f2bf(b) << 16);
}
__device__ inline float bf2f(unsigned short h) {
    unsigned u = ((unsigned)h) << 16;
    return __builtin_bit_cast(float, u);
}
// swizzled LDS element offset for [128][32] bf16 tiles; kk multiple of 8
__device__ inline int soff(int row, int kk) {
    return row * 32 + (kk ^ (((row >> 1) & 3) << 3));
}

// ---------------- kernel 1: normalize x rows -> bf16, zero out ----------------
__global__ __launch_bounds__(256) void k_norm_x(const float* __restrict__ x,
                                                unsigned short* __restrict__ XNB,
                                                float* __restrict__ out) {
    int row = blockIdx.x, tid = threadIdx.x;
    float v0 = x[row * DD + tid];
    float v1 = x[row * DD + tid + 256];
    float ss = v0 * v0 + v1 * v1;
    for (int m = 1; m < 64; m <<= 1) ss += __shfl_xor(ss, m, 64);
    __shared__ float sm[4];
    int wid = tid >> 6, lane = tid & 63;
    if (lane == 0) sm[wid] = ss;
    __syncthreads();
    float inv = 1.0f / fmaxf(sqrtf(sm[0] + sm[1] + sm[2] + sm[3]), 1e-12f);
    XNB[row * DD + tid]       = f2bf(v0 * inv);
    XNB[row * DD + tid + 256] = f2bf(v1 * inv);
    if (row == 0 && tid == 0) out[0] = 0.0f;
}

// ------------- kernel 1b (new): normalized bf16 W, zero-padded rows -------------
__global__ __launch_bounds__(256) void k_wnormc(const float* __restrict__ w,
                                                unsigned short* __restrict__ WNB) {
    int wid = threadIdx.x >> 6, lane = threadIdx.x & 63;
    int row = blockIdx.x * 4 + wid;
    uint2* o0 = (uint2*)(WNB + (size_t)row * DD) + lane;        // elems 4*lane..
    uint2* o1 = (uint2*)(WNB + (size_t)row * DD + 256) + lane;  // elems 256+4*lane..
    if (row >= CC) {
        uint2 z = make_uint2(0u, 0u);
        *o0 = z; *o1 = z;
        return;
    }
    const float4* wr = (const float4*)(w + (size_t)row * DD);
    float4 a = wr[lane];
    float4 b = wr[lane + 64];
    float ss = a.x*a.x + a.y*a.y + a.z*a.z + a.w*a.w
             + b.x*b.x + b.y*b.y + b.z*b.z + b.w*b.w;
    for (int m = 1; m < 64; m <<= 1) ss += __shfl_xor(ss, m, 64);
    float inv = 1.0f / fmaxf(sqrtf(ss), 1e-12f);
    *o0 = make_uint2(pk2(a.x*inv, a.y*inv), pk2(a.z*inv, a.w*inv));
    *o1 = make_uint2(pk2(b.x*inv, b.y*inv), pk2(b.z*inv, b.w*inv));
}

// ------------- kernel 1b (old): 1/||w_c|| (fallback path) -------------
__global__ __launch_bounds__(256) void k_wnorm(const float* __restrict__ w,
                                               float* __restrict__ WINV) {
    int wid = threadIdx.x >> 6, lane = threadIdx.x & 63;
    int row = blockIdx.x * 4 + wid;
    if (row >= CC) return;
    const float4* wr = (const float4*)(w + (size_t)row * DD);
    float4 a = wr[lane];
    float4 b = wr[lane + 64];
    float ss = a.x*a.x + a.y*a.y + a.z*a.z + a.w*a.w
             + b.x*b.x + b.y*b.y + b.z*b.z + b.w*b.w;
    for (int m = 1; m < 64; m <<= 1) ss += __shfl_xor(ss, m, 64);
    if (lane == 0) WINV[row] = 1.0f / fmaxf(sqrtf(ss), 1e-12f);
}

// ---------------- kernel 2 (new): swapped-operand bf16 MFMA + fused stats ----------------
// 1D grid 3128, XCD-chunked swizzle. Block = 4 waves (2x2), tile 128 classes x 128 batch.
// A = WNB (classes), B = XNB (batch)  ->  acc rows = classes (in-thread reduce axis).
__global__ __launch_bounds__(256) void k_gemm_bf(const unsigned short* __restrict__ WNB,
                                                 const unsigned short* __restrict__ XNB,
                                                 const float* __restrict__ rescale_p,
                                                 float* __restrict__ ZP,
                                                 float* __restrict__ S2P,
                                                 float* __restrict__ S3P) {
    __shared__ __align__(16) unsigned short Wt[128 * 32];
    __shared__ __align__(16) unsigned short Xt[128 * 32];
    __shared__ float st[2][2][64][3];   // [batch-half wc][wr][batch row][stat]

    int h = blockIdx.x;
    int logical = (h & 7) * 391 + (h >> 3);   // 3128 = 8*391, bijective
    int ct = logical >> 2;                    // class tile 0..781
    int bt = logical & 3;                     // batch tile 0..3

    int tid = threadIdx.x;
    int lane = tid & 63, wid = tid >> 6;
    int wr = wid >> 1, wc = wid & 1;          // wr: class half, wc: batch half
    float rescale = rescale_p[0];

    // staging: thread -> (row 0..127, half 0..1), 16 bf16 each
    int srow = tid & 127, half = tid >> 7;
    const uint4* wsrc = (const uint4*)(WNB + (size_t)(ct * 128 + srow) * DD + half * 16);
    const uint4* xsrc = (const uint4*)(XNB + (size_t)(bt * 128 + srow) * DD + half * 16);
    int wo0 = soff(srow, half * 16);
    int wo1 = soff(srow, half * 16 + 8);

    // fragment read offsets
    int ro[4], co[4];
#pragma unroll
    for (int i = 0; i < 4; i++) {
        ro[i] = soff(wr * 64 + i * 16 + (lane & 15), (lane >> 4) * 8);  // class frags (A)
        co[i] = soff(wc * 64 + i * 16 + (lane & 15), (lane >> 4) * 8);  // batch frags (B)
    }

    f32x4 acc[4][4];
#pragma unroll
    for (int i = 0; i < 4; i++)
#pragma unroll
        for (int j = 0; j < 4; j++) acc[i][j] = (f32x4){0.f, 0.f, 0.f, 0.f};

    uint4 Wa0, Wb0, Xa0, Xb0, Wa1, Wb1, Xa1, Xb1;
    auto LOAD = [&](uint4& Wa, uint4& Wb, uint4& Xa, uint4& Xb, int kt) {
        Wa = wsrc[kt * 4]; Wb = wsrc[kt * 4 + 1];
        Xa = xsrc[kt * 4]; Xb = xsrc[kt * 4 + 1];
    };
    auto STORE = [&](const uint4& Wa, const uint4& Wb, const uint4& Xa, const uint4& Xb) {
        *(uint4*)&Wt[wo0] = Wa; *(uint4*)&Wt[wo1] = Wb;
        *(uint4*)&Xt[wo0] = Xa; *(uint4*)&Xt[wo1] = Xb;
    };
    auto COMPUTE = [&]() {
        short8 a[4], b[4];
#pragma unroll
        for (int i = 0; i < 4; i++) a[i] = *(const short8*)&Wt[ro[i]];
#pragma unroll
        for (int i = 0; i < 4; i++) b[i] = *(const short8*)&Xt[co[i]];
#pragma unroll
        for (int i = 0; i < 4; i++)
#pragma unroll
            for (int j = 0; j < 4; j++)
                acc[i][j] = __builtin_amdgcn_mfma_f32_16x16x32_bf16(a[i], b[j], acc[i][j], 0, 0, 0);
    };

    LOAD(Wa0, Wb0, Xa0, Xb0, 0);
    for (int it = 0; it < 8; ++it) {
        int kt = it * 2;
        __syncthreads();
        STORE(Wa0, Wb0, Xa0, Xb0);
        LOAD(Wa1, Wb1, Xa1, Xb1, kt + 1);
        __syncthreads();
        COMPUTE();
        __syncthreads();
        STORE(Wa1, Wb1, Xa1, Xb1);
        if (kt + 2 < 16) LOAD(Wa0, Wb0, Xa0, Xb0, kt + 2);
        __syncthreads();
        COMPUTE();
    }

    // ---- epilogue: classes are in-thread -> cheap per-batch-col stats ----
    float mref = fabsf(rescale);
    const float L2E = 1.44269504f;
    float rs = rescale * L2E, mb = mref * L2E;
    float zz[4] = {0.f,0.f,0.f,0.f}, q2[4] = {0.f,0.f,0.f,0.f}, q3[4] = {0.f,0.f,0.f,0.f};
#pragma unroll
    for (int mi = 0; mi < 4; mi++) {
#pragma unroll
        for (int reg = 0; reg < 4; reg++) {
            int c = ct * 128 + wr * 64 + mi * 16 + (lane >> 4) * 4 + reg;
            float mask = (c < CC) ? 1.0f : 0.0f;
#pragma unroll
            for (int ni = 0; ni < 4; ni++) {
                float cosv = acc[mi][ni][reg];
                cosv = fminf(fmaxf(cosv, -1.0f + CLIP_EPS), 1.0f - CLIP_EPS);
                float e = exp2f(fmaf(cosv, rs, -mb)) * mask;
                float e2 = e * e;
                zz[ni] += e;
                q2[ni] += e2;
                q3[ni] = fmaf(e2, e, q3[ni]);
            }
        }
    }
#pragma unroll
    for (int msk = 16; msk < 64; msk <<= 1) {
#pragma unroll
        for (int ni = 0; ni < 4; ni++) {
            zz[ni] += __shfl_xor(zz[ni], msk, 64);
            q2[ni] += __shfl_xor(q2[ni], msk, 64);
            q3[ni] += __shfl_xor(q3[ni], msk, 64);
        }
    }
    if (lane < 16) {
#pragma unroll
        for (int ni = 0; ni < 4; ni++) {
            st[wc][wr][ni * 16 + lane][0] = zz[ni];
            st[wc][wr][ni * 16 + lane][1] = q2[ni];
            st[wc][wr][ni * 16 + lane][2] = q3[ni];
        }
    }
    __syncthreads();
    if (tid < 128) {
        int bh = tid >> 6, bl = tid & 63;
        float Z  = st[bh][0][bl][0] + st[bh][1][bl][0];
        float S2 = st[bh][0][bl][1] + st[bh][1][bl][1];
        float S3 = st[bh][0][bl][2] + st[bh][1][bl][2];
        size_t gi = (size_t)ct * BB + bt * 128 + tid;   // bh*64+bl == tid (tid<128)
        ZP[gi] = Z; S2P[gi] = S2; S3P[gi] = S3;
    }
}

// ---------------- kernel 2 (old, fallback): f32-W bf16 MFMA ----------------
__global__ __launch_bounds__(256) void k_gemm(const float* __restrict__ w,
                                              const float* __restrict__ rescale_p,
                                              const unsigned short* __restrict__ XNB,
                                              const float* __restrict__ WINV,
                                              float* __restrict__ ZP,
                                              float* __restrict__ S2P,
                                              float* __restrict__ S3P) {
    __shared__ __align__(16) unsigned short As[128 * 32];
    __shared__ __align__(16) unsigned short Bs[128 * 32];
    __shared__ float st[2][2][64][3];

    int tid = threadIdx.x;
    int lane = tid & 63, wid = tid >> 6;
    int wr = wid >> 1, wc = wid & 1;
    int rowbase = blockIdx.x * 128;
    int colbase = blockIdx.y * 128;
    float rescale = rescale_p[0];

    int srow = tid & 127, half = tid >> 7;
    const uint4* asrc = (const uint4*)(XNB + (size_t)(rowbase + srow) * DD + half * 16);
    int cg = colbase + srow;
    int cgc = cg < CC ? cg : CC - 1;
    const float4* bsrc = (const float4*)(w + (size_t)cgc * DD + half * 16);
    int wo0 = soff(srow, half * 16);
    int wo1 = soff(srow, half * 16 + 8);

    int ro[4], co[4];
#pragma unroll
    for (int i = 0; i < 4; i++) {
        ro[i] = soff(wr * 64 + i * 16 + (lane & 15), (lane >> 4) * 8);
        co[i] = soff(wc * 64 + i * 16 + (lane & 15), (lane >> 4) * 8);
    }

    f32x4 acc[4][4];
#pragma unroll
    for (int i = 0; i < 4; i++)
#pragma unroll
        for (int j = 0; j < 4; j++) acc[i][j] = (f32x4){0.f, 0.f, 0.f, 0.f};

    uint4 Aa0, Ab0, Aa1, Ab1;
    float4 Bf0[4], Bf1[4];
    auto LOAD = [&](uint4& Aa, uint4& Ab, float4* Bf, int kt) {
        Aa = asrc[kt * 4]; Ab = asrc[kt * 4 + 1];
#pragma unroll
        for (int i = 0; i < 4; i++) Bf[i] = bsrc[kt * 8 + i];
    };
    auto STORE = [&](const uint4& Aa, const uint4& Ab, const float4* Bf) {
        *(uint4*)&As[wo0] = Aa; *(uint4*)&As[wo1] = Ab;
        uint4 lo, hi;
        lo.x = pk2(Bf[0].x, Bf[0].y); lo.y = pk2(Bf[0].z, Bf[0].w);
        lo.z = pk2(Bf[1].x, Bf[1].y); lo.w = pk2(Bf[1].z, Bf[1].w);
        hi.x = pk2(Bf[2].x, Bf[2].y); hi.y = pk2(Bf[2].z, Bf[2].w);
        hi.z = pk2(Bf[3].x, Bf[3].y); hi.w = pk2(Bf[3].z, Bf[3].w);
        *(uint4*)&Bs[wo0] = lo; *(uint4*)&Bs[wo1] = hi;
    };
    auto COMPUTE = [&]() {
        short8 a[4], b[4];
#pragma unroll
        for (int i = 0; i < 4; i++) a[i] = *(const short8*)&As[ro[i]];
#pragma unroll
        for (int i = 0; i < 4; i++) b[i] = *(const short8*)&Bs[co[i]];
#pragma unroll
        for (int i = 0; i < 4; i++)
#pragma unroll
            for (int j = 0; j < 4; j++)
                acc[i][j] = __builtin_amdgcn_mfma_f32_16x16x32_bf16(a[i], b[j], acc[i][j], 0, 0, 0);
    };

    LOAD(Aa0, Ab0, Bf0, 0);
    for (int it = 0; it < 8; ++it) {
        int kt = it * 2;
        __syncthreads();
        STORE(Aa0, Ab0, Bf0);
        LOAD(Aa1, Ab1, Bf1, kt + 1);
        __syncthreads();
        COMPUTE();
        __syncthreads();
        STORE(Aa1, Ab1, Bf1);
        if (kt + 2 < 16) LOAD(Aa0, Ab0, Bf0, kt + 2);
        __syncthreads();
        COMPUTE();
    }

    float wv[4]; int cvalid[4];
#pragma unroll
    for (int ni = 0; ni < 4; ni++) {
        int c = colbase + wc * 64 + ni * 16 + (lane & 15);
        cvalid[ni] = (c < CC);
        wv[ni] = cvalid[ni] ? WINV[c] : 0.0f;
    }
    float mref = fabsf(rescale);
#pragma unroll
    for (int mi = 0; mi < 4; mi++) {
#pragma unroll
        for (int reg = 0; reg < 4; reg++) {
            float zz = 0.f, q2 = 0.f, q3 = 0.f;
#pragma unroll
            for (int ni = 0; ni < 4; ni++) {
                if (cvalid[ni]) {
                    float cosv = acc[mi][ni][reg] * wv[ni];
                    cosv = fminf(fmaxf(cosv, -1.0f + CLIP_EPS), 1.0f - CLIP_EPS);
                    float e = __expf(rescale * cosv - mref);
                    zz += e; float e2 = e * e; q2 += e2; q3 += e2 * e;
                }
            }
#pragma unroll
            for (int msk = 1; msk < 16; msk <<= 1) {
                zz += __shfl_xor(zz, msk, 64);
                q2 += __shfl_xor(q2, msk, 64);
                q3 += __shfl_xor(q3, msk, 64);
            }
            if ((lane & 15) == 0) {
                int rl = mi * 16 + (lane >> 4) * 4 + reg;
                st[wr][wc][rl][0] = zz; st[wr][wc][rl][1] = q2; st[wr][wc][rl][2] = q3;
            }
        }
    }
    __syncthreads();
    if (tid < 128) {
        int wrr = tid >> 6, rl = tid & 63;
        float Z  = st[wrr][0][rl][0] + st[wrr][1][rl][0];
        float S2 = st[wrr][0][rl][1] + st[wrr][1][rl][1];
        float S3 = st[wrr][0][rl][2] + st[wrr][1][rl][2];
        size_t gi = (size_t)blockIdx.y * BB + rowbase + tid;
        ZP[gi] = Z; S2P[gi] = S2; S3P[gi] = S3;
    }
}

// ---------------- kernel 3: combine partials, margin fixup, loss ----------------
__global__ __launch_bounds__(256) void k_final(const float* __restrict__ w,
                                               const int* __restrict__ y,
                                               const float* __restrict__ rescale_p,
                                               const unsigned short* __restrict__ XNB,
                                               const float* __restrict__ ZP,
                                               const float* __restrict__ S2P,
                                               const float* __restrict__ S3P,
                                               float* __restrict__ out) {
    int b = blockIdx.x, tid = threadIdx.x;
    int yb = y[b];

    float d0 = 0.f, q0 = 0.f;
#pragma unroll
    for (int i = 0; i < 2; i++) {
        int idx = tid + i * 256;
        float xv = bf2f(XNB[b * DD + idx]);
        float wvv = w[(size_t)yb * DD + idx];
        d0 = fmaf(xv, wvv, d0);
        q0 = fmaf(wvv, wvv, q0);
    }
    for (int m = 1; m < 64; m <<= 1) { d0 += __shfl_xor(d0, m, 64); q0 += __shfl_xor(q0, m, 64); }
    __shared__ float sd[4], sq[4], szs[4], s2s[4], s3s[4];
    int wid = tid >> 6, lane = tid & 63;
    if (lane == 0) { sd[wid] = d0; sq[wid] = q0; }

    float rz = 0.f, r2 = 0.f, r3 = 0.f;
    for (int ch = tid; ch < NCOLT; ch += 256) {
        size_t gi = (size_t)ch * BB + b;
        rz += ZP[gi]; r2 += S2P[gi]; r3 += S3P[gi];
    }
    for (int m = 1; m < 64; m <<= 1) {
        rz += __shfl_xor(rz, m, 64);
        r2 += __shfl_xor(r2, m, 64);
        r3 += __shfl_xor(r3, m, 64);
    }
    if (lane == 0) { szs[wid] = rz; s2s[wid] = r2; s3s[wid] = r3; }
    __syncthreads();

    if (tid == 0) {
        float Z  = szs[0] + szs[1] + szs[2] + szs[3];
        float S2 = s2s[0] + s2s[1] + s2s[2] + s2s[3];
        float S3 = s3s[0] + s3s[1] + s3s[2] + s3s[3];
        float dot = sd[0] + sd[1] + sd[2] + sd[3];
        float ssq = sq[0] + sq[1] + sq[2] + sq[3];
        float rescale = rescale_p[0];
        float mref = fabsf(rescale);
        float winv = 1.0f / fmaxf(sqrtf(ssq), 1e-12f);
        float fc = fminf(fmaxf(dot * winv, -1.0f + CLIP_EPS), 1.0f - CLIP_EPS);
        float su = rescale * fc;
        float fcm = fc * cosf(MARGIN) - sqrtf(fmaxf(1.0f - fc * fc, 0.0f)) * sinf(MARGIN);
        float smv = rescale * fcm;
        float eU = __expf(su - mref), eM = __expf(smv - mref);
        Z  += eM - eU;
        S2 += eM * eM - eU * eU;
        S3 += eM * eM * eM - eU * eU * eU;
        float py = eM / Z;
        float sumexp = (float)CC + 1.0f + S2 / (2.0f * Z * Z) + S3 / (6.0f * Z * Z * Z);
        float nll = logf(sumexp) - py;
        atomicAdd(out, nll * (1.0f / (float)BB));
    }
}

extern "C" void kernel_launch(void* const* d_in, const int* in_sizes, int n_in,
                              void* d_out, int out_size, void* d_ws, size_t ws_size,
                              hipStream_t stream) {
    const float* x       = (const float*)d_in[0];
    const int*   y       = (const int*)  d_in[1];
    const float* w       = (const float*)d_in[2];
    const float* rescale = (const float*)d_in[3];
    float* out = (float*)d_out;
    char*  wsb = (char*)d_ws;

    unsigned short* XNB = (unsigned short*)(wsb);
    float* ZP  = (float*)(wsb + PBASE);
    float* S2P = (float*)(wsb + PBASE + P_BYTES);
    float* S3P = (float*)(wsb + PBASE + 2u * P_BYTES);

    k_norm_x<<<dim3(BB), dim3(256), 0, stream>>>(x, XNB, out);

    if (ws_size >= NEED_NEW) {
        unsigned short* WNB = (unsigned short*)(wsb + AUX_OFF);
        k_wnormc <<<dim3(CCPAD / 4), dim3(256), 0, stream>>>(w, WNB);
        k_gemm_bf<<<dim3(8 * 391), dim3(256), 0, stream>>>(WNB, XNB, rescale, ZP, S2P, S3P);
    } else {
        float* WINV = (float*)(wsb + AUX_OFF);
        k_wnorm<<<dim3((CC + 3) / 4), dim3(256), 0, stream>>>(w, WINV);
        k_gemm <<<dim3(4, NCOLT), dim3(256), 0, stream>>>(w, rescale, XNB, WINV, ZP, S2P, S3P);
    }
    k_final<<<dim3(BB), dim3(256), 0, stream>>>(w, y, rescale, XNB, ZP, S2P, S3P, out);
}